// Round 3
// baseline (148.833 us; speedup 1.0000x reference)
//
#include <hip/hip_runtime.h>

#define BLOCK 256

typedef float fvec4 __attribute__((ext_vector_type(4)));

// tanh(x) = 1 - 2/(exp(2x)+1); exact at +-inf limits.
__device__ __forceinline__ float fast_tanh(float x) {
    float e = __expf(2.0f * x);
    return 1.0f - 2.0f * __builtin_amdgcn_rcpf(e + 1.0f);
}

// <Zi>,<Zj>,<ZiZj> for Ry(ta) x Ry(tb)|00> followed by matchgate(th, phi1, phi2).
__device__ __forceinline__ void pair_z(float ta, float tb, float th, float phi1, float phi2,
                                       float& zi, float& zj, float& zz) {
    float ca, sa, cb, sb, c, s;
    __sincosf(0.5f * ta, &sa, &ca);
    __sincosf(0.5f * tb, &sb, &cb);
    __sincosf(0.5f * th, &s, &c);
    float cp1 = __cosf(phi1);
    float cp2 = __cosf(phi2);

    float u = ca * sb, v = sa * cb;
    float p0 = ca * cb; p0 *= p0;
    float p3 = sa * sb; p3 *= p3;
    float u2 = u * u, v2 = v * v, c2 = c * c, s2 = s * s;
    float cs2uv = 2.0f * c * s * u * v;
    float p1 = c2 * u2 + s2 * v2 - cs2uv * cp1;
    float p2 = s2 * u2 + c2 * v2 + cs2uv * cp2;

    zi = p0 + p1 - p2 - p3;
    zj = p0 - p1 + p2 - p3;
    zz = p0 - p1 - p2 + p3;
}

// 10 inputs (raw x values) -> 10 outputs for one row.
__device__ __forceinline__ void row_out(float f0, float f1, float f2, float f3, float f4,
                                        float f5, float f6, float f7, float f8, float f9,
                                        float o[10]) {
    float t0 = 0.5f * fast_tanh(f0);
    float t1 = 0.5f * fast_tanh(f1);
    float t2 = 0.5f * fast_tanh(f2);
    float t3 = 0.5f * fast_tanh(f3);
    float t4 = 0.5f * fast_tanh(f4);
    float t5 = 0.5f * fast_tanh(f5);
    float t6 = 0.5f * fast_tanh(f6);
    float t7 = 0.5f * fast_tanh(f7);
    float t8 = 0.5f * fast_tanh(f8);
    float t9 = 0.5f * fast_tanh(f9);

    float z0, z1, zz01, z2, z3, zz23;
    pair_z(t0, t1, t4, t5, t6, z0, z1, zz01);
    pair_z(t2, t3, t7, t8, t9, z2, z3, zz23);

    o[0] = z0; o[1] = z1; o[2] = z2; o[3] = z3;
    o[4] = zz01; o[5] = z0 * z2; o[6] = z0 * z3;
    o[7] = z1 * z2; o[8] = z1 * z3; o[9] = zz23;
}

__device__ __forceinline__ void nt_store4(float* p, float a, float b, float c, float d) {
    fvec4 v = {a, b, c, d};
    __builtin_nontemporal_store(v, reinterpret_cast<fvec4*>(p));
}

__global__ void __launch_bounds__(BLOCK)
qfm_kernel(const float* __restrict__ x, float* __restrict__ out, int npairs) {
    int stride = gridDim.x * blockDim.x;
    for (int p = blockIdx.x * blockDim.x + threadIdx.x; p < npairs; p += stride) {
        // 2 rows = 20 floats = 80 B, 16B-aligned -> 5x float4 loads
        const fvec4* xp = reinterpret_cast<const fvec4*>(x + (size_t)p * 20);
        fvec4 a0 = xp[0], a1 = xp[1], a2 = xp[2], a3 = xp[3], a4 = xp[4];

        float oA[10], oB[10];
        row_out(a0.x, a0.y, a0.z, a0.w, a1.x, a1.y, a1.z, a1.w, a2.x, a2.y, oA);
        row_out(a2.z, a2.w, a3.x, a3.y, a3.z, a3.w, a4.x, a4.y, a4.z, a4.w, oB);

        float* op = out + (size_t)p * 20;
        nt_store4(op +  0, oA[0], oA[1], oA[2], oA[3]);
        nt_store4(op +  4, oA[4], oA[5], oA[6], oA[7]);
        nt_store4(op +  8, oA[8], oA[9], oB[0], oB[1]);
        nt_store4(op + 12, oB[2], oB[3], oB[4], oB[5]);
        nt_store4(op + 16, oB[6], oB[7], oB[8], oB[9]);
    }
}

// Handles the last row if B is odd (not expected for B=2^21, but safe).
__global__ void qfm_tail(const float* __restrict__ x, float* __restrict__ out, int row) {
    if (threadIdx.x == 0 && blockIdx.x == 0) {
        const float* xr = x + (size_t)row * 10;
        float o[10];
        row_out(xr[0], xr[1], xr[2], xr[3], xr[4], xr[5], xr[6], xr[7], xr[8], xr[9], o);
        float* orow = out + (size_t)row * 10;
        #pragma unroll
        for (int i = 0; i < 10; ++i) orow[i] = o[i];
    }
}

extern "C" void kernel_launch(void* const* d_in, const int* in_sizes, int n_in,
                              void* d_out, int out_size, void* d_ws, size_t ws_size,
                              hipStream_t stream) {
    const float* x = (const float*)d_in[0];
    float* out = (float*)d_out;
    int B = in_sizes[0] / 10;
    int npairs = B / 2;
    int blocks = (npairs + BLOCK - 1) / BLOCK;
    if (blocks > 2048) blocks = 2048;
    qfm_kernel<<<blocks, BLOCK, 0, stream>>>(x, out, npairs);
    if (B & 1) qfm_tail<<<1, 64, 0, stream>>>(x, out, B - 1);
}

// Round 5
// 36.944 us; speedup vs baseline: 4.0286x; 4.0286x over previous
//
#include <hip/hip_runtime.h>

#define BLOCK 256

typedef float fvec4 __attribute__((ext_vector_type(4)));

// tanh(x) = 1 - 2/(exp(2x)+1); exact at +-inf limits.
__device__ __forceinline__ float fast_tanh(float x) {
    float e = __expf(2.0f * x);
    return 1.0f - 2.0f * __builtin_amdgcn_rcpf(e + 1.0f);
}

// <Zi>,<Zj>,<ZiZj> for Ry(ta) x Ry(tb)|00> followed by matchgate(th, phi1, phi2).
__device__ __forceinline__ void pair_z(float ta, float tb, float th, float phi1, float phi2,
                                       float& zi, float& zj, float& zz) {
    float ca, sa, cb, sb, c, s;
    __sincosf(0.5f * ta, &sa, &ca);
    __sincosf(0.5f * tb, &sb, &cb);
    __sincosf(0.5f * th, &s, &c);
    float cp1 = __cosf(phi1);
    float cp2 = __cosf(phi2);

    float u = ca * sb, v = sa * cb;
    float p0 = ca * cb; p0 *= p0;
    float p3 = sa * sb; p3 *= p3;
    float u2 = u * u, v2 = v * v, c2 = c * c, s2 = s * s;
    float cs2uv = 2.0f * c * s * u * v;
    float p1 = c2 * u2 + s2 * v2 - cs2uv * cp1;
    float p2 = s2 * u2 + c2 * v2 + cs2uv * cp2;

    zi = p0 + p1 - p2 - p3;
    zj = p0 - p1 + p2 - p3;
    zz = p0 - p1 - p2 + p3;
}

// 10 inputs (raw x values) -> 10 outputs for one row.
__device__ __forceinline__ void row_out(float f0, float f1, float f2, float f3, float f4,
                                        float f5, float f6, float f7, float f8, float f9,
                                        float o[10]) {
    float t0 = 0.5f * fast_tanh(f0);
    float t1 = 0.5f * fast_tanh(f1);
    float t2 = 0.5f * fast_tanh(f2);
    float t3 = 0.5f * fast_tanh(f3);
    float t4 = 0.5f * fast_tanh(f4);
    float t5 = 0.5f * fast_tanh(f5);
    float t6 = 0.5f * fast_tanh(f6);
    float t7 = 0.5f * fast_tanh(f7);
    float t8 = 0.5f * fast_tanh(f8);
    float t9 = 0.5f * fast_tanh(f9);

    float z0, z1, zz01, z2, z3, zz23;
    pair_z(t0, t1, t4, t5, t6, z0, z1, zz01);
    pair_z(t2, t3, t7, t8, t9, z2, z3, zz23);

    o[0] = z0; o[1] = z1; o[2] = z2; o[3] = z3;
    o[4] = zz01; o[5] = z0 * z2; o[6] = z0 * z3;
    o[7] = z1 * z2; o[8] = z1 * z3; o[9] = zz23;
}

__global__ void __launch_bounds__(BLOCK)
qfm_kernel(const float* __restrict__ x, float* __restrict__ out, int npairs) {
    int stride = gridDim.x * blockDim.x;
    for (int p = blockIdx.x * blockDim.x + threadIdx.x; p < npairs; p += stride) {
        // 2 rows = 20 floats = 80 B, 16B-aligned -> 5x float4 loads
        const fvec4* xp = reinterpret_cast<const fvec4*>(x + (size_t)p * 20);
        fvec4 a0 = xp[0], a1 = xp[1], a2 = xp[2], a3 = xp[3], a4 = xp[4];

        float oA[10], oB[10];
        row_out(a0.x, a0.y, a0.z, a0.w, a1.x, a1.y, a1.z, a1.w, a2.x, a2.y, oA);
        row_out(a2.z, a2.w, a3.x, a3.y, a3.z, a3.w, a4.x, a4.y, a4.z, a4.w, oB);

        fvec4* op = reinterpret_cast<fvec4*>(out + (size_t)p * 20);
        op[0] = fvec4{oA[0], oA[1], oA[2], oA[3]};
        op[1] = fvec4{oA[4], oA[5], oA[6], oA[7]};
        op[2] = fvec4{oA[8], oA[9], oB[0], oB[1]};
        op[3] = fvec4{oB[2], oB[3], oB[4], oB[5]};
        op[4] = fvec4{oB[6], oB[7], oB[8], oB[9]};
    }
}

// Handles the last row if B is odd (not expected for B=2^21, but safe).
__global__ void qfm_tail(const float* __restrict__ x, float* __restrict__ out, int row) {
    if (threadIdx.x == 0 && blockIdx.x == 0) {
        const float* xr = x + (size_t)row * 10;
        float o[10];
        row_out(xr[0], xr[1], xr[2], xr[3], xr[4], xr[5], xr[6], xr[7], xr[8], xr[9], o);
        float* orow = out + (size_t)row * 10;
        #pragma unroll
        for (int i = 0; i < 10; ++i) orow[i] = o[i];
    }
}

extern "C" void kernel_launch(void* const* d_in, const int* in_sizes, int n_in,
                              void* d_out, int out_size, void* d_ws, size_t ws_size,
                              hipStream_t stream) {
    const float* x = (const float*)d_in[0];
    float* out = (float*)d_out;
    int B = in_sizes[0] / 10;
    int npairs = B / 2;
    int blocks = (npairs + BLOCK - 1) / BLOCK;
    if (blocks > 2048) blocks = 2048;
    qfm_kernel<<<blocks, BLOCK, 0, stream>>>(x, out, npairs);
    if (B & 1) qfm_tail<<<1, 64, 0, stream>>>(x, out, B - 1);
}

// Round 6
// 30.771 us; speedup vs baseline: 4.8367x; 1.2006x over previous
//
#include <hip/hip_runtime.h>

#define BLOCK 256
#define ROWS_PER_CHUNK 512                 // 2 rows per thread
#define CHUNK_FLOATS (ROWS_PER_CHUNK * 10) // 5120 floats = 20 KB LDS

typedef float fvec4 __attribute__((ext_vector_type(4)));

// tanh(x) = 1 - 2/(exp(2x)+1); exact at +-inf limits.
__device__ __forceinline__ float fast_tanh(float x) {
    float e = __expf(2.0f * x);
    return 1.0f - 2.0f * __builtin_amdgcn_rcpf(e + 1.0f);
}

// <Zi>,<Zj>,<ZiZj> for Ry(ta) x Ry(tb)|00> followed by matchgate(th, phi1, phi2).
__device__ __forceinline__ void pair_z(float ta, float tb, float th, float phi1, float phi2,
                                       float& zi, float& zj, float& zz) {
    float ca, sa, cb, sb, c, s;
    __sincosf(0.5f * ta, &sa, &ca);
    __sincosf(0.5f * tb, &sb, &cb);
    __sincosf(0.5f * th, &s, &c);
    float cp1 = __cosf(phi1);
    float cp2 = __cosf(phi2);

    float u = ca * sb, v = sa * cb;
    float p0 = ca * cb; p0 *= p0;
    float p3 = sa * sb; p3 *= p3;
    float u2 = u * u, v2 = v * v, c2 = c * c, s2 = s * s;
    float cs2uv = 2.0f * c * s * u * v;
    float p1 = c2 * u2 + s2 * v2 - cs2uv * cp1;
    float p2 = s2 * u2 + c2 * v2 + cs2uv * cp2;

    zi = p0 + p1 - p2 - p3;
    zj = p0 - p1 + p2 - p3;
    zz = p0 - p1 - p2 + p3;
}

// 10 raw x values -> 10 outputs for one row.
__device__ __forceinline__ void row_out(const float f[10], float o[10]) {
    float t0 = 0.5f * fast_tanh(f[0]);
    float t1 = 0.5f * fast_tanh(f[1]);
    float t2 = 0.5f * fast_tanh(f[2]);
    float t3 = 0.5f * fast_tanh(f[3]);
    float t4 = 0.5f * fast_tanh(f[4]);
    float t5 = 0.5f * fast_tanh(f[5]);
    float t6 = 0.5f * fast_tanh(f[6]);
    float t7 = 0.5f * fast_tanh(f[7]);
    float t8 = 0.5f * fast_tanh(f[8]);
    float t9 = 0.5f * fast_tanh(f[9]);

    float z0, z1, zz01, z2, z3, zz23;
    pair_z(t0, t1, t4, t5, t6, z0, z1, zz01);
    pair_z(t2, t3, t7, t8, t9, z2, z3, zz23);

    o[0] = z0; o[1] = z1; o[2] = z2; o[3] = z3;
    o[4] = zz01; o[5] = z0 * z2; o[6] = z0 * z3;
    o[7] = z1 * z2; o[8] = z1 * z3; o[9] = zz23;
}

__global__ void __launch_bounds__(BLOCK)
qfm_kernel(const float* __restrict__ x, float* __restrict__ out, int nchunks) {
    __shared__ float lds[CHUNK_FLOATS];
    const int tid = threadIdx.x;

    for (int chunk = blockIdx.x; chunk < nchunks; chunk += gridDim.x) {
        const size_t base = (size_t)chunk * CHUNK_FLOATS;

        // Phase 1: dense cooperative load, 5 x (256 threads x 16 B) = 20 KB.
        const fvec4* gin = reinterpret_cast<const fvec4*>(x + base);
        fvec4* lv = reinterpret_cast<fvec4*>(lds);
        #pragma unroll
        for (int r = 0; r < 5; ++r)
            lv[r * BLOCK + tid] = gin[r * BLOCK + tid];
        __syncthreads();

        // Phase 2: each thread consumes its 2 rows (20 floats @ 80B, 16B-aligned).
        float in[20];
        const fvec4* lrow = reinterpret_cast<const fvec4*>(lds + tid * 20);
        #pragma unroll
        for (int k = 0; k < 5; ++k) {
            fvec4 v = lrow[k];
            in[4 * k + 0] = v.x; in[4 * k + 1] = v.y;
            in[4 * k + 2] = v.z; in[4 * k + 3] = v.w;
        }
        float oA[10], oB[10];
        row_out(in, oA);
        row_out(in + 10, oB);
        __syncthreads();  // all reads done before overwriting LDS

        fvec4* lw = reinterpret_cast<fvec4*>(lds + tid * 20);
        lw[0] = fvec4{oA[0], oA[1], oA[2], oA[3]};
        lw[1] = fvec4{oA[4], oA[5], oA[6], oA[7]};
        lw[2] = fvec4{oA[8], oA[9], oB[0], oB[1]};
        lw[3] = fvec4{oB[2], oB[3], oB[4], oB[5]};
        lw[4] = fvec4{oB[6], oB[7], oB[8], oB[9]};
        __syncthreads();

        // Phase 3: dense non-temporal store (full 128B lines -> no amplification,
        // and the output stream does not evict the input from L3).
        fvec4* gout = reinterpret_cast<fvec4*>(out + base);
        #pragma unroll
        for (int r = 0; r < 5; ++r)
            __builtin_nontemporal_store(lv[r * BLOCK + tid], gout + r * BLOCK + tid);
        // No barrier needed here: phase-3 reads and next phase-1 writes hit the
        // same addresses from the SAME thread (r*BLOCK+tid), no cross-thread hazard.
    }
}

// Handles leftover rows (B not a multiple of 512). One row per thread, scalar.
__global__ void qfm_tail(const float* __restrict__ x, float* __restrict__ out,
                         int row0, int B) {
    int row = row0 + blockIdx.x * blockDim.x + threadIdx.x;
    if (row >= B) return;
    const float* xr = x + (size_t)row * 10;
    float f[10], o[10];
    #pragma unroll
    for (int i = 0; i < 10; ++i) f[i] = xr[i];
    row_out(f, o);
    float* orow = out + (size_t)row * 10;
    #pragma unroll
    for (int i = 0; i < 10; ++i) orow[i] = o[i];
}

extern "C" void kernel_launch(void* const* d_in, const int* in_sizes, int n_in,
                              void* d_out, int out_size, void* d_ws, size_t ws_size,
                              hipStream_t stream) {
    const float* x = (const float*)d_in[0];
    float* out = (float*)d_out;
    int B = in_sizes[0] / 10;
    int nchunks = B / ROWS_PER_CHUNK;
    int blocks = nchunks < 2048 ? (nchunks > 0 ? nchunks : 1) : 2048;
    if (nchunks > 0)
        qfm_kernel<<<blocks, BLOCK, 0, stream>>>(x, out, nchunks);
    int done = nchunks * ROWS_PER_CHUNK;
    int rem = B - done;
    if (rem > 0) {
        int tblocks = (rem + BLOCK - 1) / BLOCK;
        qfm_tail<<<tblocks, BLOCK, 0, stream>>>(x, out, done, B);
    }
}

// Round 7
// 30.541 us; speedup vs baseline: 4.8733x; 1.0076x over previous
//
#include <hip/hip_runtime.h>

#define BLOCK 256
#define ROWS_PER_CHUNK 512                 // 2 rows per thread
#define CHUNK_FLOATS (ROWS_PER_CHUNK * 10) // 5120 floats = 20 KB LDS

typedef float fvec4 __attribute__((ext_vector_type(4)));

// tanh(x) = 1 - 2/(exp(2x)+1); exact at +-inf limits.
__device__ __forceinline__ float fast_tanh(float x) {
    float e = __expf(2.0f * x);
    return 1.0f - 2.0f * __builtin_amdgcn_rcpf(e + 1.0f);
}

// <Zi>,<Zj>,<ZiZj> for Ry(ta) x Ry(tb)|00> followed by matchgate(th, phi1, phi2).
__device__ __forceinline__ void pair_z(float ta, float tb, float th, float phi1, float phi2,
                                       float& zi, float& zj, float& zz) {
    float ca, sa, cb, sb, c, s;
    __sincosf(0.5f * ta, &sa, &ca);
    __sincosf(0.5f * tb, &sb, &cb);
    __sincosf(0.5f * th, &s, &c);
    float cp1 = __cosf(phi1);
    float cp2 = __cosf(phi2);

    float u = ca * sb, v = sa * cb;
    float p0 = ca * cb; p0 *= p0;
    float p3 = sa * sb; p3 *= p3;
    float u2 = u * u, v2 = v * v, c2 = c * c, s2 = s * s;
    float cs2uv = 2.0f * c * s * u * v;
    float p1 = c2 * u2 + s2 * v2 - cs2uv * cp1;
    float p2 = s2 * u2 + c2 * v2 + cs2uv * cp2;

    zi = p0 + p1 - p2 - p3;
    zj = p0 - p1 + p2 - p3;
    zz = p0 - p1 - p2 + p3;
}

// 10 raw x values -> 10 outputs for one row.
__device__ __forceinline__ void row_out(const float f[10], float o[10]) {
    float t0 = 0.5f * fast_tanh(f[0]);
    float t1 = 0.5f * fast_tanh(f[1]);
    float t2 = 0.5f * fast_tanh(f[2]);
    float t3 = 0.5f * fast_tanh(f[3]);
    float t4 = 0.5f * fast_tanh(f[4]);
    float t5 = 0.5f * fast_tanh(f[5]);
    float t6 = 0.5f * fast_tanh(f[6]);
    float t7 = 0.5f * fast_tanh(f[7]);
    float t8 = 0.5f * fast_tanh(f[8]);
    float t9 = 0.5f * fast_tanh(f[9]);

    float z0, z1, zz01, z2, z3, zz23;
    pair_z(t0, t1, t4, t5, t6, z0, z1, zz01);
    pair_z(t2, t3, t7, t8, t9, z2, z3, zz23);

    o[0] = z0; o[1] = z1; o[2] = z2; o[3] = z3;
    o[4] = zz01; o[5] = z0 * z2; o[6] = z0 * z3;
    o[7] = z1 * z2; o[8] = z1 * z3; o[9] = zz23;
}

__global__ void __launch_bounds__(BLOCK)
qfm_kernel(const float* __restrict__ x, float* __restrict__ out, int nchunks) {
    __shared__ float lds[CHUNK_FLOATS];
    const int tid = threadIdx.x;
    const int chunk = blockIdx.x;
    if (chunk >= nchunks) return;
    const size_t base = (size_t)chunk * CHUNK_FLOATS;

    // Phase 1: async HBM->LDS DMA, 5 x (64 lanes x 16 B) per wave, fully linear.
    // LDS dest is wave-uniform base + lane*16 (the required global_load_lds layout).
    const float* gsrc = x + base;
    const int wave_base = tid & ~63;
    #pragma unroll
    for (int r = 0; r < 5; ++r) {
        __builtin_amdgcn_global_load_lds(
            (const __attribute__((address_space(1))) void*)(gsrc + (size_t)(r * BLOCK + tid) * 4),
            (__attribute__((address_space(3))) void*)(lds + (r * BLOCK + wave_base) * 4),
            16, 0, 0);
    }
    __syncthreads();  // drains vmcnt (global_load_lds) before any LDS read

    // Phase 2: each thread consumes its own 2 rows (20 floats @ 80B, 16B-aligned),
    // then writes results back over the SAME private 80B region — no barrier needed
    // between the read and the write (no cross-thread access until phase 3).
    float in[20];
    const fvec4* lrow = reinterpret_cast<const fvec4*>(lds + tid * 20);
    #pragma unroll
    for (int k = 0; k < 5; ++k) {
        fvec4 v = lrow[k];
        in[4 * k + 0] = v.x; in[4 * k + 1] = v.y;
        in[4 * k + 2] = v.z; in[4 * k + 3] = v.w;
    }
    float oA[10], oB[10];
    row_out(in, oA);
    row_out(in + 10, oB);

    fvec4* lw = reinterpret_cast<fvec4*>(lds + tid * 20);
    lw[0] = fvec4{oA[0], oA[1], oA[2], oA[3]};
    lw[1] = fvec4{oA[4], oA[5], oA[6], oA[7]};
    lw[2] = fvec4{oA[8], oA[9], oB[0], oB[1]};
    lw[3] = fvec4{oB[2], oB[3], oB[4], oB[5]};
    lw[4] = fvec4{oB[6], oB[7], oB[8], oB[9]};
    __syncthreads();  // phase-3 reads other threads' regions

    // Phase 3: dense full-line non-temporal stores (R6-verified: WRITE stays ~82 MB).
    const fvec4* lv = reinterpret_cast<const fvec4*>(lds);
    fvec4* gout = reinterpret_cast<fvec4*>(out + base);
    #pragma unroll
    for (int r = 0; r < 5; ++r)
        __builtin_nontemporal_store(lv[r * BLOCK + tid], gout + r * BLOCK + tid);
}

// Handles leftover rows (B not a multiple of 512). One row per thread, scalar.
__global__ void qfm_tail(const float* __restrict__ x, float* __restrict__ out,
                         int row0, int B) {
    int row = row0 + blockIdx.x * blockDim.x + threadIdx.x;
    if (row >= B) return;
    const float* xr = x + (size_t)row * 10;
    float f[10], o[10];
    #pragma unroll
    for (int i = 0; i < 10; ++i) f[i] = xr[i];
    row_out(f, o);
    float* orow = out + (size_t)row * 10;
    #pragma unroll
    for (int i = 0; i < 10; ++i) orow[i] = o[i];
}

extern "C" void kernel_launch(void* const* d_in, const int* in_sizes, int n_in,
                              void* d_out, int out_size, void* d_ws, size_t ws_size,
                              hipStream_t stream) {
    const float* x = (const float*)d_in[0];
    float* out = (float*)d_out;
    int B = in_sizes[0] / 10;
    int nchunks = B / ROWS_PER_CHUNK;
    if (nchunks > 0)
        qfm_kernel<<<nchunks, BLOCK, 0, stream>>>(x, out, nchunks);
    int done = nchunks * ROWS_PER_CHUNK;
    int rem = B - done;
    if (rem > 0) {
        int tblocks = (rem + BLOCK - 1) / BLOCK;
        qfm_tail<<<tblocks, BLOCK, 0, stream>>>(x, out, done, B);
    }
}